// Round 3
// baseline (189.424 us; speedup 1.0000x reference)
//
#include <hip/hip_runtime.h>
#include <math.h>

typedef short short8 __attribute__((ext_vector_type(8)));
typedef float f32x16 __attribute__((ext_vector_type(16)));

#define BB 16
#define CC 256
#define HH 64
#define WW 64
#define HWX 4096
#define DD 4
#define KD 9
#define KK 81
#define CHALF 128

__device__ __forceinline__ unsigned short f2bf(float x) {
    union { float f; unsigned u; } v; v.f = x;
    unsigned r = v.u + 0x7FFFu + ((v.u >> 16) & 1u);   // RNE
    return (unsigned short)(r >> 16);
}

union LdsU {
    unsigned short A[WW * CC];                               // 32 KB (prologue only)
    struct { unsigned short B0[WW * CHALF], B1[WW * CHALF]; } bb; // 16+16 KB
};

// stage one c-half (128 ch) of a B row into buf (bf16, [w][cc] with 4-bit XOR swz)
__device__ __forceinline__ void stage_half(const float* __restrict__ srcB,
                                           unsigned short* buf, float* partRow,
                                           int wv, int l, int hf) {
    float ss = 0.f;
    #pragma unroll
    for (int r = 0; r < 4; ++r) {
        const int cc = wv * 32 + r * 8;
        float v[8]; short8 st;
        #pragma unroll
        for (int j = 0; j < 8; ++j) {
            v[j] = srcB[(size_t)(hf * CHALF + cc + j) * HWX + l];
            ss += v[j] * v[j];
        }
        #pragma unroll
        for (int j = 0; j < 8; ++j) st[j] = (short)f2bf(v[j]);
        const int byte = (l * 256 + cc * 2) ^ ((l & 15) << 4);
        *(short8*)((char*)buf + byte) = st;
    }
    partRow[wv * 64 + l] = ss;
}

__device__ __forceinline__ void mfma_half(const unsigned short* buf,
                                          const short8* afrh, int n, int kg,
                                          f32x16& acc0, f32x16& acc1) {
    #pragma unroll
    for (int s = 0; s < 8; s += 2) {
        const int byte0 = (n * 256 + s * 32 + kg * 16) ^ ((n & 15) << 4);
        const int byte1 = (n * 256 + (s + 1) * 32 + kg * 16) ^ ((n & 15) << 4);
        short8 b0 = *(const short8*)((const char*)buf + byte0);
        short8 b1 = *(const short8*)((const char*)buf + byte1);
        acc0 = __builtin_amdgcn_mfma_f32_32x32x16_bf16(afrh[s], b0, acc0, 0, 0, 0);
        acc1 = __builtin_amdgcn_mfma_f32_32x32x16_bf16(afrh[s + 1], b1, acc1, 0, 0, 0);
    }
}

__global__ __launch_bounds__(256, 4) void corr_mfma(
    const float* __restrict__ fA, const float* __restrict__ fB,
    float* __restrict__ out)
{
    __shared__ __attribute__((aligned(16))) LdsU u;
    __shared__ float red[KD][WW];          // 2.25 KB banded outputs for one dy
    __shared__ float part0[4 * WW], part1[4 * WW];
    __shared__ float invA_ls[WW];

    // XCD-aware swizzle: 1024 blocks, 8 XCDs (1024%8==0 -> bijective)
    const int bid = blockIdx.x;
    const int swz = (bid & 7) * 128 + (bid >> 3);
    const int b = swz >> 6, h = swz & 63;

    const int tid = threadIdx.x;
    const int wv = tid >> 6, l = tid & 63;

    // ---- prologue: stage A row (full 256c, 5-bit swz), invA, hoist frags ----
    {
        const float* Abase = fA + (size_t)b * CC * HWX + h * WW;
        float ss = 0.f;
        #pragma unroll
        for (int r = 0; r < 8; ++r) {
            const int c0 = wv * 64 + r * 8;
            float v[8]; short8 st;
            #pragma unroll
            for (int j = 0; j < 8; ++j) {
                v[j] = Abase[(size_t)(c0 + j) * HWX + l];
                ss += v[j] * v[j];
            }
            #pragma unroll
            for (int j = 0; j < 8; ++j) st[j] = (short)f2bf(v[j]);
            const int byte = (l * 512 + c0 * 2) ^ ((l & 31) << 4);
            *(short8*)((char*)u.A + byte) = st;
        }
        part0[wv * 64 + l] = ss;
    }
    __syncthreads();

    const int ti = wv >> 1, tj = wv & 1;     // wave quadrant of the 64x64 gram
    const int ml = l & 31, kg = l >> 5;
    const int m = ti * 32 + ml;              // A row (w)
    const int n = tj * 32 + ml;              // B row (w')

    if (tid < WW) {
        float s = part0[tid] + part0[64 + tid] + part0[128 + tid] + part0[192 + tid];
        invA_ls[tid] = 1.f / fmaxf(sqrtf(s), 1e-12f);
    }
    short8 afr[16];
    #pragma unroll
    for (int s = 0; s < 16; ++s) {
        const int byte = (m * 512 + s * 32 + kg * 16) ^ ((m & 31) << 4);
        afr[s] = *(const short8*)((const char*)u.A + byte);
    }
    // zero red once; boundary entries stay zero forever
    for (int i = tid; i < KD * WW; i += 256) ((float*)red)[i] = 0.f;
    __syncthreads();   // A-region reads complete before B0 overwrites

    // ---- dy loop ----
    for (int dy = 0; dy < KD; ++dy) {
        const int hB = h + dy - DD;
        float* obase = out + (((size_t)b * KK + dy * KD) * HH + h) * WW;
        if (hB >= 0 && hB < HH) {
            const float* srcB = fB + (size_t)b * CC * HWX + (size_t)hB * WW;

            stage_half(srcB, u.bb.B0, part0, wv, l, 0);
            __syncthreads();                       // B0 + part0 ready

            f32x16 acc0, acc1;
            #pragma unroll
            for (int i = 0; i < 16; ++i) { acc0[i] = 0.f; acc1[i] = 0.f; }

            // stage half1 (loads fly under MFMA of half0)
            stage_half(srcB, u.bb.B1, part1, wv, l, 1);
            mfma_half(u.bb.B0, afr, n, kg, acc0, acc1);
            __syncthreads();                       // B1 + part1 ready

            mfma_half(u.bb.B1, afr + 8, n, kg, acc0, acc1);

            // band epilogue: per-lane invB at n, write banded entries
            float sB = 0.f;
            #pragma unroll
            for (int q = 0; q < 4; ++q) sB += part0[q * 64 + n] + part1[q * 64 + n];
            const float ibn = 1.f / fmaxf(sqrtf(sB), 1e-12f);
            #pragma unroll
            for (int r = 0; r < 16; ++r) {
                // D layout (m74/m101): col = lane&31 (=w'), row = (r&3)+8*(r>>2)+4*kg
                const int w = ti * 32 + (r & 3) + 8 * (r >> 2) + 4 * kg;
                const int dx = n - w + 4;
                if (dx >= 0 && dx < KD)
                    red[dx][w] = (acc0[r] + acc1[r]) * invA_ls[w] * ibn;
            }
            __syncthreads();                       // red complete
            for (int i = tid; i < KD * WW; i += 256)
                obase[(size_t)(i >> 6) * HWX + (i & 63)] = ((float*)red)[i];
        } else {
            // whole dy-plane is zero padding; out is poisoned so must write
            for (int i = tid; i < KD * WW; i += 256)
                obase[(size_t)(i >> 6) * HWX + (i & 63)] = 0.f;
        }
    }
}

extern "C" void kernel_launch(void* const* d_in, const int* in_sizes, int n_in,
                              void* d_out, int out_size, void* d_ws, size_t ws_size,
                              hipStream_t stream) {
    const float* fA = (const float*)d_in[0];
    const float* fB = (const float*)d_in[1];
    float* outp = (float*)d_out;
    corr_mfma<<<dim3(BB * HH), 256, 0, stream>>>(fA, fB, outp);
}

// Round 4
// 80.589 us; speedup vs baseline: 2.3505x; 2.3505x over previous
//
#include <hip/hip_runtime.h>
#include <math.h>

typedef short short8 __attribute__((ext_vector_type(8)));
typedef float f32x16 __attribute__((ext_vector_type(16)));

#define BB 16
#define CC 256
#define HH 64
#define WW 64
#define HWX 4096
#define DD 4
#define KD 9
#define KK 81

__device__ __forceinline__ unsigned short f2bf(float x) {
    union { float f; unsigned u; } v; v.f = x;
    unsigned r = v.u + 0x7FFFu + ((v.u >> 16) & 1u);   // RNE
    return (unsigned short)(r >> 16);
}

// Stage one c-half (128 ch) of a B row into the FULL-STRIDE (512 B/row) LDS
// tile, occupying column range [hf*128, hf*128+128). 5-bit XOR swizzle ->
// conflict-free (2 lanes/bank). Lane l owns w=l; wave wv owns 32 channels.
__device__ __forceinline__ void stage_half(const float* __restrict__ src,
                                           unsigned short* buf, float* part,
                                           int wv, int l, int hf) {
    float ss = 0.f;
    #pragma unroll
    for (int r = 0; r < 4; ++r) {
        const int c = hf * 128 + wv * 32 + r * 8;
        float v[8]; short8 st;
        #pragma unroll
        for (int j = 0; j < 8; ++j) {
            v[j] = src[(size_t)(c + j) * HWX + l];
            ss += v[j] * v[j];
        }
        #pragma unroll
        for (int j = 0; j < 8; ++j) st[j] = (short)f2bf(v[j]);
        const int byte = (l * 512 + c * 2) ^ ((l & 31) << 4);
        *(short8*)((char*)buf + byte) = st;
    }
    part[wv * 64 + l] = ss;
}

// 8 MFMAs over k-slices [sbase, sbase+8) of the 64x64 gram quadrant.
__device__ __forceinline__ void mfma_half(const unsigned short* buf,
                                          const short8* afr, int sbase,
                                          int n, int kg, f32x16& acc) {
    #pragma unroll
    for (int s = sbase; s < sbase + 8; ++s) {
        const int byte = (n * 512 + s * 32 + kg * 16) ^ ((n & 31) << 4);
        short8 bf = *(const short8*)((const char*)buf + byte);
        acc = __builtin_amdgcn_mfma_f32_32x32x16_bf16(afr[s], bf, acc, 0, 0, 0);
    }
}

__global__ __launch_bounds__(256) void corr_mfma(
    const float* __restrict__ fA, const float* __restrict__ fB,
    float* __restrict__ out)
{
    __shared__ __attribute__((aligned(16))) unsigned short Bls[WW * CC]; // 32 KB (A in prologue, then B)
    __shared__ float red[KD][WW];          // banded outputs for one dy
    __shared__ float part0[2][4 * WW];     // half0 sumsq partials, dy-parity dbuf
    __shared__ float part1[4 * WW];        // half1 sumsq partials (also A partials)
    __shared__ float invA_ls[WW];

    // XCD-aware swizzle: 1024 blocks, 8 XCDs (1024 % 8 == 0 -> bijective)
    const int bid = blockIdx.x;
    const int swz = (bid & 7) * 128 + (bid >> 3);
    const int b = swz >> 6, h = swz & 63;

    const int tid = threadIdx.x;
    const int wv = tid >> 6, l = tid & 63;
    const int ti = wv >> 1, tj = wv & 1;     // wave quadrant of the 64x64 gram
    const int ml = l & 31, kg = l >> 5;
    const int m = ti * 32 + ml;              // A row (w)
    const int n = tj * 32 + ml;              // B row (w')

    // ---- prologue: stage A row (full 256c), invA, hoist A fragments ----
    {
        const float* Abase = fA + (size_t)b * CC * HWX + h * WW;
        float ss = 0.f;
        #pragma unroll
        for (int r = 0; r < 8; ++r) {
            const int c = wv * 64 + r * 8;
            float v[8]; short8 st;
            #pragma unroll
            for (int j = 0; j < 8; ++j) {
                v[j] = Abase[(size_t)(c + j) * HWX + l];
                ss += v[j] * v[j];
            }
            #pragma unroll
            for (int j = 0; j < 8; ++j) st[j] = (short)f2bf(v[j]);
            const int byte = (l * 512 + c * 2) ^ ((l & 31) << 4);
            *(short8*)((char*)Bls + byte) = st;
        }
        part1[wv * 64 + l] = ss;
    }
    __syncthreads();
    if (tid < WW) {
        float s = part1[tid] + part1[64 + tid] + part1[128 + tid] + part1[192 + tid];
        invA_ls[tid] = 1.f / fmaxf(sqrtf(s), 1e-12f);
    }
    short8 afr[16];
    #pragma unroll
    for (int s = 0; s < 16; ++s) {
        const int byte = (m * 512 + s * 32 + kg * 16) ^ ((m & 31) << 4);
        afr[s] = *(const short8*)((const char*)Bls + byte);
    }
    // zero red once; entries outside the band stay zero forever
    for (int i = tid; i < KD * WW; i += 256) ((float*)red)[i] = 0.f;
    __syncthreads();   // all A-region reads complete before B overwrites

    const float* fBb = fB + (size_t)b * CC * HWX;
    if ((unsigned)(h - DD) < HH)             // valid(dy=0)
        stage_half(fBb + (size_t)(h - DD) * WW, Bls, part0[0], wv, l, 0);
    __syncthreads();

    // ---- dy loop: 2 barriers per dy, all staging overlapped with MFMA ----
    for (int dy = 0; dy < KD; ++dy) {
        const int hB = h + dy - DD;
        float* obase = out + (((size_t)b * KK + dy * KD) * HH + h) * WW;
        const bool vcur = (unsigned)hB < HH;                       // block-uniform
        const bool vnext = (dy < KD - 1) && ((unsigned)(hB + 1) < HH);
        if (vcur) {
            f32x16 acc;
            #pragma unroll
            for (int i = 0; i < 16; ++i) acc[i] = 0.f;
            // phase B: stage half1 (loads fly under MFMA of half0)
            stage_half(fBb + (size_t)hB * WW, Bls, part1, wv, l, 1);
            mfma_half(Bls, afr, 0, n, kg, acc);
            __syncthreads();                   // half1 ready; half0 cols now dead
            // phase C: prefetch next dy's half0 under MFMA of half1
            if (vnext)
                stage_half(fBb + (size_t)(hB + 1) * WW, Bls, part0[(dy + 1) & 1], wv, l, 0);
            mfma_half(Bls, afr, 8, n, kg, acc);
            // per-lane invB at row n
            float sB = 0.f;
            #pragma unroll
            for (int q = 0; q < 4; ++q)
                sB += part0[dy & 1][q * 64 + n] + part1[q * 64 + n];
            const float ibn = 1.f / fmaxf(sqrtf(sB), 1e-12f);
            #pragma unroll
            for (int r = 0; r < 16; ++r) {
                // D layout (m74/m101): col = lane&31 (=w'), row = (r&3)+8*(r>>2)+4*kg
                const int w = ti * 32 + (r & 3) + 8 * (r >> 2) + 4 * kg;
                const int dx = n - w + 4;
                if (dx >= 0 && dx < KD)
                    red[dx][w] = acc[r] * invA_ls[w] * ibn;
            }
            __syncthreads();                   // red complete, prefetch staged
            for (int i = tid; i < KD * WW; i += 256)
                obase[(size_t)(i >> 6) * HWX + (i & 63)] = ((float*)red)[i];
        } else {
            // whole dy-plane is zero padding; still prefetch next half0
            if (vnext)
                stage_half(fBb + (size_t)(hB + 1) * WW, Bls, part0[(dy + 1) & 1], wv, l, 0);
            for (int i = tid; i < KD * WW; i += 256)
                obase[(size_t)(i >> 6) * HWX + (i & 63)] = 0.f;
            __syncthreads();                   // prefetch staged before next phase B
        }
    }
}

extern "C" void kernel_launch(void* const* d_in, const int* in_sizes, int n_in,
                              void* d_out, int out_size, void* d_ws, size_t ws_size,
                              hipStream_t stream) {
    const float* fA = (const float*)d_in[0];
    const float* fB = (const float*)d_in[1];
    float* outp = (float*)d_out;
    corr_mfma<<<dim3(BB * HH), 256, 0, stream>>>(fA, fB, outp);
}